// Round 11
// baseline (162.307 us; speedup 1.0000x reference)
//
#include <hip/hip_runtime.h>

// ContrastiveLoss: B=8192, D=128, T=0.1, SINGLE_POS=False.
// Classes c = 2*tt + tp in {0..3}; pos class = c^1, neg class = c^2.
// Rows counting-sorted by class; each wave visits only the <=2 relevant
// column segments. B staged per 64-row panel via global_load_lds (single
// 16KB buffer). waves_per_eu(4,4) pins the 128-VGPR budget (r8: (4,8)
// clamps to 64 VGPR and spills 68MB). Finalize folded into sim via
// last-arriving-block counter (verified pattern, r2) — saves one dispatch.

#define NB 8192
#define ND 128
#define NIB 64          // i-blocks (128 rows each)
#define JS 16           // j-slices -> grid 64*16 = 1024 blocks (4/CU)
#define NH 8            // classify histogram groups (1024 rows each)
#define TEMP_INV 10.0f
#define LOG2E 1.4426950408889634f
#define EXPK (TEMP_INV * LOG2E)

typedef __attribute__((ext_vector_type(8))) short short8;
typedef __attribute__((ext_vector_type(4))) float f32x4;

// ws layout (bytes)
#define OFF_G    0                         // 8192*128 bf16 = 2 MB
#define OFF_CLS  (NB * ND * 2)             // sorted classes u8[8192]
#define OFF_CNT  (OFF_CLS + NB)            // per-h class hist int[NH*4]
#define OFF_DONE (OFF_CNT + 128)           // arrival counter int[1]
#define OFF_EPP  (OFF_CNT + 256)           // JS*8192 f32 partials
#define OFF_ENP  (OFF_EPP + NB * 4 * JS)
#define OFF_LSP  (OFF_ENP + NB * 4 * JS)
// aliased into the Ep partial region (dead before sim overwrites every slot):
#define OFF_CO   OFF_EPP                   // original classes u8[8192]
#define OFF_RL   (OFF_EPP + NB)            // local rank in (h,class) u16[8192]

__device__ __forceinline__ unsigned short f2bf(float x) {
    unsigned int u = __float_as_uint(x);
    unsigned int r = (u + 0x7FFFu + ((u >> 16) & 1u)) >> 16;  // RNE
    return (unsigned short)r;
}

__device__ __forceinline__ float fast_exp2(float x) {
#if __has_builtin(__builtin_amdgcn_exp2f)
    return __builtin_amdgcn_exp2f(x);
#else
    return exp2f(x);
#endif
}

typedef const __attribute__((address_space(1))) void gas_void;
typedef __attribute__((address_space(3))) void las_void;
__device__ __forceinline__ void gload_lds16(const void* g, void* s) {
    // width-16 global->LDS DMA; LDS dest = uniform base + lane*16 (HW rule)
    __builtin_amdgcn_global_load_lds((gas_void*)g, (las_void*)s, 16, 0, 0);
}

// 8 blocks x 1024 (1 row/thread): classes, per-(h,class) hist + local ranks.
__global__ __launch_bounds__(1024) void classify_kernel(
    const int* __restrict__ dix, const int* __restrict__ tt, const int* __restrict__ tp,
    unsigned char* __restrict__ clsO, unsigned short* __restrict__ rlocal,
    int* __restrict__ cntP, int* __restrict__ done, float* __restrict__ out)
{
    __shared__ int lh[4];
    const int h = blockIdx.x, tid = threadIdx.x;
    if (tid < 4) lh[tid] = 0;
    __syncthreads();
    const int row = h * 1024 + tid;
    const int ix  = dix[row];
    const int c   = ((tt[ix] & 1) << 1) | (tp[ix] & 1);
    clsO[row] = (unsigned char)c;
    rlocal[row] = (unsigned short)atomicAdd(&lh[c], 1);
    if (h == 0 && tid == 0) { *out = 0.0f; *done = 0; }
    __syncthreads();
    if (tid < 4) cntP[h * 4 + tid] = lh[tid];
}

// 512 blocks x 256 (wave per row, 4 rows per wave): normalize + scatter.
__global__ __launch_bounds__(256) void normscatter_kernel(
    const float* __restrict__ F, const unsigned char* __restrict__ clsO,
    const unsigned short* __restrict__ rlocal, const int* __restrict__ cntP,
    unsigned short* __restrict__ G, unsigned char* __restrict__ clsS)
{
    const int wave = threadIdx.x >> 6, lane = threadIdx.x & 63;
    #pragma unroll
    for (int k = 0; k < 4; ++k) {
        const int row = blockIdx.x * 16 + k * 4 + wave;
        const int c = clsO[row];
        const int h = row >> 10;                 // 1024 rows per hist group
        int base = (int)rlocal[row];
        #pragma unroll
        for (int cc = 0; cc < 3; ++cc)           // classes below c (wave-uniform)
            if (cc < c) {
                #pragma unroll
                for (int hh = 0; hh < NH; ++hh) base += cntP[hh * 4 + cc];
            }
        #pragma unroll
        for (int hh = 0; hh < NH - 1; ++hh)      // earlier hist groups, same class
            if (hh < h) base += cntP[hh * 4 + c];

        const float2 v = *(const float2*)(F + row * ND + lane * 2);
        float ss = v.x * v.x + v.y * v.y;
        #pragma unroll
        for (int m = 1; m < 64; m <<= 1) ss += __shfl_xor(ss, m, 64);
        const float inv = rsqrtf(fmaxf(ss, 1e-24f));
        ushort2 st; st.x = f2bf(v.x * inv); st.y = f2bf(v.y * inv);
        *(ushort2*)(G + base * ND + lane * 2) = st;
        if (lane == 0) clsS[base] = (unsigned char)c;
    }
}

// Stage one 64-row panel: wave wu stages rows wu*16..wu*16+15.
// Lane l -> row pr = wu*16 + 4*j + (l>>4), slot l&15 holds global chunk
// (slot - pr) & 15  (rotation; read side applies the same permutation).
__device__ __forceinline__ void stage_panel(
    const unsigned short* __restrict__ G, unsigned short* Blds,
    int rbase, int wu, int lrow4, int lpos)
{
    #pragma unroll
    for (int j = 0; j < 4; ++j) {
        const int pr = wu * 16 + j * 4 + lrow4;
        int rowG = rbase + pr;
        rowG = (rowG < NB - 1) ? rowG : (NB - 1);   // clamp (masked in compute)
        const int chunk = (lpos - pr) & 15;
        gload_lds16(G + rowG * ND + chunk * 8, Blds + (wu * 16 + j * 4) * ND);
    }
}

// MODE: 0 = stage-only (inactive wave), 1 = POS (Ep,Ls), 2 = NEG (En),
// 3 = weighted both (straddling waves only — rare after sorting).
template<int MODE>
__device__ __forceinline__ void seg_panels(
    const unsigned short* __restrict__ G, unsigned short* Blds,
    const short8 (&A)[2][4],
    float (&Ep)[8], float (&En)[8], float (&Ls)[8],
    const float (&wp)[8], const float (&wn)[8],
    int cs, int ce, int p0, int p1, int wu, int lane)
{
    const int lrow4 = lane >> 4, lpos = lane & 15;
    const int q = lane >> 4, l16 = lane & 15;
    #pragma unroll 1
    for (int p = p0; p < p1; ++p) {
        stage_panel(G, Blds, cs + p * 64, wu, lrow4, lpos);
        __syncthreads();                   // vmcnt(0): panel ready
        if (MODE != 0) {
            #pragma unroll
            for (int st = 0; st < 4; ++st) {
                const int j0 = cs + p * 64 + st * 16;
                if (j0 >= ce) break;       // wave-uniform tail cutoff
                short8 Bf[4];
                #pragma unroll
                for (int c = 0; c < 4; ++c) {
                    const int slot = (c * 4 + q + l16) & 15;    // rotation
                    Bf[c] = *(const short8*)&Blds[(st * 16 + l16) * ND + slot * 8];
                }
                f32x4 acc0 = {0.f, 0.f, 0.f, 0.f}, acc1 = {0.f, 0.f, 0.f, 0.f};
                #pragma unroll
                for (int c = 0; c < 4; ++c)
                    acc0 = __builtin_amdgcn_mfma_f32_16x16x32_bf16(A[0][c], Bf[c], acc0, 0, 0, 0);
                #pragma unroll
                for (int c = 0; c < 4; ++c)
                    acc1 = __builtin_amdgcn_mfma_f32_16x16x32_bf16(A[1][c], Bf[c], acc1, 0, 0, 0);
                if (j0 + 16 <= ce) {       // full subtile
                    #pragma unroll
                    for (int r = 0; r < 4; ++r) {
                        const float sv0 = acc0[r], sv1 = acc1[r];
                        const float e0 = fast_exp2(sv0 * EXPK);
                        const float e1 = fast_exp2(sv1 * EXPK);
                        if (MODE == 1) {
                            Ep[r] += e0;      Ls[r] += sv0;
                            Ep[4 + r] += e1;  Ls[4 + r] += sv1;
                        } else if (MODE == 2) {
                            En[r] += e0;      En[4 + r] += e1;
                        } else {
                            Ep[r]     = fmaf(wp[r],     e0,  Ep[r]);
                            Ls[r]     = fmaf(wp[r],     sv0, Ls[r]);
                            Ep[4 + r] = fmaf(wp[4 + r], e1,  Ep[4 + r]);
                            Ls[4 + r] = fmaf(wp[4 + r], sv1, Ls[4 + r]);
                            En[r]     = fmaf(wn[r],     e0, En[r]);
                            En[4 + r] = fmaf(wn[4 + r], e1, En[4 + r]);
                        }
                    }
                } else {                   // masked tail subtile
                    const float vm = ((j0 + l16) < ce) ? 1.f : 0.f;
                    #pragma unroll
                    for (int r = 0; r < 4; ++r) {
                        const float sv0 = acc0[r] * vm, sv1 = acc1[r] * vm;
                        const float e0 = fast_exp2(sv0 * EXPK) * vm;
                        const float e1 = fast_exp2(sv1 * EXPK) * vm;
                        if (MODE == 1) {
                            Ep[r] += e0;      Ls[r] += sv0;
                            Ep[4 + r] += e1;  Ls[4 + r] += sv1;
                        } else if (MODE == 2) {
                            En[r] += e0;      En[4 + r] += e1;
                        } else {
                            Ep[r]     = fmaf(wp[r],     e0,  Ep[r]);
                            Ls[r]     = fmaf(wp[r],     sv0, Ls[r]);
                            Ep[4 + r] = fmaf(wp[4 + r], e1,  Ep[4 + r]);
                            Ls[4 + r] = fmaf(wp[4 + r], sv1, Ls[4 + r]);
                            En[r]     = fmaf(wn[r],     e0, En[r]);
                            En[4 + r] = fmaf(wn[4 + r], e1, En[4 + r]);
                        }
                    }
                }
            }
        }
        __syncthreads();                   // all waves done reading panel
    }
}

// Grid 64 i-blocks x 16 j-slices = 1024 blocks (4/CU).
// Last arriving block folds the finalize (saves one dispatch boundary).
__global__ __launch_bounds__(256) __attribute__((amdgpu_waves_per_eu(4, 4)))
void sim_kernel(
    const unsigned short* __restrict__ G, const unsigned char* __restrict__ clsS,
    const int* __restrict__ cntP, int* __restrict__ done,
    float* __restrict__ EpP, float* __restrict__ EnP, float* __restrict__ LsP,
    float* __restrict__ out)
{
    __shared__ unsigned short Blds[64 * 128];   // 16 KB single buffer

    const int ib = blockIdx.x & (NIB - 1);
    const int jb = blockIdx.x >> 6;          // 0..JS-1
    const int wave = threadIdx.x >> 6, lane = threadIdx.x & 63;
    const int q = lane >> 4, l16 = lane & 15;
    const int ri = ib * 128 + wave * 32;
    const int wu = __builtin_amdgcn_readfirstlane(wave);

    short8 A[2][4];
    #pragma unroll
    for (int t = 0; t < 2; ++t)
        #pragma unroll
        for (int c = 0; c < 4; ++c)
            A[t][c] = *(const short8*)(G + (ri + 16 * t + l16) * ND + c * 32 + q * 8);

    // this lane's 8 output-row classes (C/D row = 16t + 4q + r)
    const unsigned int rcLo = *(const unsigned int*)(clsS + ri + 4 * q);
    const unsigned int rcHi = *(const unsigned int*)(clsS + ri + 16 + 4 * q);
    const int wF = clsS[ri], wL = clsS[ri + 31];              // wave class range
    const int bF = clsS[ib * 128], bL = clsS[ib * 128 + 127]; // block class range

    float Ep[8], En[8], Ls[8];
    #pragma unroll
    for (int i = 0; i < 8; ++i) { Ep[i] = 0.f; En[i] = 0.f; Ls[i] = 0.f; }
    float wp[8], wn[8];   // written only on the (rare) straddle path

    int cs = 0;
    #pragma unroll 1
    for (int s = 0; s < 4; ++s) {
        int len = 0;
        #pragma unroll
        for (int h = 0; h < NH; ++h) len += cntP[h * 4 + s];
        const int ce = cs + len;
        const int s1 = s ^ 1, s2 = s ^ 2;
        const bool aPb = (s1 >= bF) && (s1 <= bL);   // block-uniform activity
        const bool aNb = (s2 >= bF) && (s2 <= bL);
        if (aPb || aNb) {
            const int np = (len + 63) >> 6;          // 64-row panels
            const int p0 = (jb * np) >> 4;           // this block's panel range
            const int p1 = ((jb + 1) * np) >> 4;
            if (p0 < p1) {
                if (wF == wL) {                       // pure-class wave (common)
                    if (s1 == wF)
                        seg_panels<1>(G, Blds, A, Ep, En, Ls, wp, wn, cs, ce, p0, p1, wu, lane);
                    else if (s2 == wF)
                        seg_panels<2>(G, Blds, A, Ep, En, Ls, wp, wn, cs, ce, p0, p1, wu, lane);
                    else
                        seg_panels<0>(G, Blds, A, Ep, En, Ls, wp, wn, cs, ce, p0, p1, wu, lane);
                } else {                              // straddling wave (rare)
                    #pragma unroll
                    for (int r = 0; r < 4; ++r) {
                        const int cLo = (rcLo >> (8 * r)) & 0xff;
                        const int cHi = (rcHi >> (8 * r)) & 0xff;
                        wp[r]     = (cLo == s1) ? 1.f : 0.f;
                        wp[4 + r] = (cHi == s1) ? 1.f : 0.f;
                        wn[r]     = (cLo == s2) ? 1.f : 0.f;
                        wn[4 + r] = (cHi == s2) ? 1.f : 0.f;
                    }
                    seg_panels<3>(G, Blds, A, Ep, En, Ls, wp, wn, cs, ce, p0, p1, wu, lane);
                }
            }
        }
        cs = ce;
    }

    // reduce across the 16 column-lanes
    #pragma unroll
    for (int m = 1; m < 16; m <<= 1)
        #pragma unroll
        for (int i = 0; i < 8; ++i) {
            Ep[i] += __shfl_xor(Ep[i], m, 64);
            En[i] += __shfl_xor(En[i], m, 64);
            Ls[i] += __shfl_xor(Ls[i], m, 64);
        }
    if (l16 == 0) {
        #pragma unroll
        for (int t = 0; t < 2; ++t)
            #pragma unroll
            for (int r = 0; r < 4; ++r) {
                const int row = ri + 16 * t + 4 * q + r;
                const int i = t * 4 + r;
                EpP[jb * NB + row] = Ep[i];   // plain stores, unique writer
                EnP[jb * NB + row] = En[i];
                LsP[jb * NB + row] = Ls[i];
            }
    }

    // ---- last arriving block computes the loss (no spin, no deadlock) ----
    __shared__ int lastFlag;
    __shared__ float wsum[4];
    __syncthreads();
    if (threadIdx.x == 0) {
        __threadfence();                       // release partial stores
        const int prev = atomicAdd(done, 1);   // device scope
        lastFlag = (prev == (int)gridDim.x - 1) ? 1 : 0;
    }
    __syncthreads();
    if (!lastFlag) return;
    __threadfence();                           // acquire others' stores

    const int tid = threadIdx.x;
    int tot[4] = {0, 0, 0, 0};
    #pragma unroll
    for (int hh = 0; hh < NH; ++hh)
        #pragma unroll
        for (int cc = 0; cc < 4; ++cc) tot[cc] += cntP[hh * 4 + cc];
    float csum = 0.f;
    #pragma unroll 1
    for (int k = 0; k < 32; ++k) {
        const int i = k * 256 + tid;
        float ep = 0.f, en = 0.f, ls = 0.f;
        #pragma unroll
        for (int jb2 = 0; jb2 < JS; ++jb2) {
            ep += __hip_atomic_load(&EpP[jb2 * NB + i], __ATOMIC_RELAXED, __HIP_MEMORY_SCOPE_AGENT);
            en += __hip_atomic_load(&EnP[jb2 * NB + i], __ATOMIC_RELAXED, __HIP_MEMORY_SCOPE_AGENT);
            ls += __hip_atomic_load(&LsP[jb2 * NB + i], __ATOMIC_RELAXED, __HIP_MEMORY_SCOPE_AGENT);
        }
        const int c = clsS[i];
        const int pc = c ^ 1, nc = c ^ 2;
        const int pcnt = (pc == 0) ? tot[0] : (pc == 1) ? tot[1] : (pc == 2) ? tot[2] : tot[3];
        const int ncnt = (nc == 0) ? tot[0] : (nc == 1) ? tot[1] : (nc == 2) ? tot[2] : tot[3];
        if (pcnt > 0 && ncnt > 0) {
            const float ld = logf(ep + en);
            csum += (TEMP_INV * ls - (float)pcnt * ld) / (float)pcnt;
        }
    }
    #pragma unroll
    for (int m = 1; m < 64; m <<= 1) csum += __shfl_xor(csum, m, 64);
    if ((tid & 63) == 0) wsum[tid >> 6] = csum;
    __syncthreads();
    if (tid == 0)
        *out = -(wsum[0] + wsum[1] + wsum[2] + wsum[3]) / (float)NB;
}

extern "C" void kernel_launch(void* const* d_in, const int* in_sizes, int n_in,
                              void* d_out, int out_size, void* d_ws, size_t ws_size,
                              hipStream_t stream) {
    const float* F = (const float*)d_in[0];
    const int* dix = (const int*)d_in[1];
    const int* tt  = (const int*)d_in[2];
    const int* tp  = (const int*)d_in[3];
    float* out = (float*)d_out;

    char* ws = (char*)d_ws;
    unsigned short* G   = (unsigned short*)(ws + OFF_G);
    unsigned char* clsS = (unsigned char*)(ws + OFF_CLS);
    int* cntP           = (int*)(ws + OFF_CNT);
    int* done           = (int*)(ws + OFF_DONE);
    float* EpP          = (float*)(ws + OFF_EPP);
    float* EnP          = (float*)(ws + OFF_ENP);
    float* LsP          = (float*)(ws + OFF_LSP);
    unsigned char* clsO = (unsigned char*)(ws + OFF_CO);   // aliases EpP (dead
    unsigned short* rl  = (unsigned short*)(ws + OFF_RL);  //  before sim writes)

    classify_kernel<<<NH, 1024, 0, stream>>>(dix, tt, tp, clsO, rl, cntP, done, out);
    normscatter_kernel<<<512, 256, 0, stream>>>(F, clsO, rl, cntP, G, clsS);
    sim_kernel<<<NIB * JS, 256, 0, stream>>>(G, clsS, cntP, done, EpP, EnP, LsP, out);
}

// Round 12
// 101.980 us; speedup vs baseline: 1.5916x; 1.5916x over previous
//
#include <hip/hip_runtime.h>

// ContrastiveLoss: B=8192, D=128, T=0.1, SINGLE_POS=False.
// Classes c = 2*tt + tp in {0..3}; pos class = c^1, neg class = c^2.
// Rows counting-sorted by class; each wave visits only the <=2 relevant
// column segments. B staged per 64-row panel via global_load_lds into a
// DOUBLE-buffered LDS (T3 2-phase: issue next panel's DMA before computing
// the current one; one vmcnt-draining __syncthreads per panel).
// Pure-class waves (common after sorting) use unweighted epilogues.
// [Verbatim resubmit of the 102.78-us best: rounds 8-10 experiments
//  (JS=32 TLP, waves(4,4), finalize-fold) all regressed via VGPR spill.]

#define NB 8192
#define ND 128
#define NIB 64          // i-blocks (128 rows each)
#define JS 16           // j-slices -> grid 64*16 = 1024 blocks (4/CU)
#define NH 8            // classify histogram groups (1024 rows each)
#define TEMP_INV 10.0f
#define LOG2E 1.4426950408889634f
#define EXPK (TEMP_INV * LOG2E)

typedef __attribute__((ext_vector_type(8))) short short8;
typedef __attribute__((ext_vector_type(4))) float f32x4;

// ws layout (bytes)
#define OFF_G    0                         // 8192*128 bf16 = 2 MB
#define OFF_CLS  (NB * ND * 2)             // sorted classes u8[8192]
#define OFF_CNT  (OFF_CLS + NB)            // per-h class hist int[NH*4]
#define OFF_EPP  (OFF_CNT + 128)           // JS*8192 f32 partials
#define OFF_ENP  (OFF_EPP + NB * 4 * JS)
#define OFF_LSP  (OFF_ENP + NB * 4 * JS)
// aliased into the Ep partial region (dead before sim overwrites every slot):
#define OFF_CO   OFF_EPP                   // original classes u8[8192]
#define OFF_RL   (OFF_EPP + NB)            // local rank in (h,class) u16[8192]

__device__ __forceinline__ unsigned short f2bf(float x) {
    unsigned int u = __float_as_uint(x);
    unsigned int r = (u + 0x7FFFu + ((u >> 16) & 1u)) >> 16;  // RNE
    return (unsigned short)r;
}

__device__ __forceinline__ float fast_exp2(float x) {
#if __has_builtin(__builtin_amdgcn_exp2f)
    return __builtin_amdgcn_exp2f(x);
#else
    return exp2f(x);
#endif
}

typedef const __attribute__((address_space(1))) void gas_void;
typedef __attribute__((address_space(3))) void las_void;
__device__ __forceinline__ void gload_lds16(const void* g, void* s) {
    // width-16 global->LDS DMA; LDS dest = uniform base + lane*16 (HW rule)
    __builtin_amdgcn_global_load_lds((gas_void*)g, (las_void*)s, 16, 0, 0);
}

// 8 blocks x 1024 (1 row/thread): classes, per-(h,class) hist + local ranks.
__global__ __launch_bounds__(1024) void classify_kernel(
    const int* __restrict__ dix, const int* __restrict__ tt, const int* __restrict__ tp,
    unsigned char* __restrict__ clsO, unsigned short* __restrict__ rlocal,
    int* __restrict__ cntP, float* __restrict__ out)
{
    __shared__ int lh[4];
    const int h = blockIdx.x, tid = threadIdx.x;
    if (tid < 4) lh[tid] = 0;
    __syncthreads();
    const int row = h * 1024 + tid;
    const int ix  = dix[row];
    const int c   = ((tt[ix] & 1) << 1) | (tp[ix] & 1);
    clsO[row] = (unsigned char)c;
    rlocal[row] = (unsigned short)atomicAdd(&lh[c], 1);
    if (h == 0 && tid == 0) *out = 0.0f;
    __syncthreads();
    if (tid < 4) cntP[h * 4 + tid] = lh[tid];
}

// 2048 blocks x 256 (wave per row): normalize row, scatter to sorted slot.
__global__ __launch_bounds__(256) void normscatter_kernel(
    const float* __restrict__ F, const unsigned char* __restrict__ clsO,
    const unsigned short* __restrict__ rlocal, const int* __restrict__ cntP,
    unsigned short* __restrict__ G, unsigned char* __restrict__ clsS)
{
    const int row  = blockIdx.x * 4 + (threadIdx.x >> 6);
    const int lane = threadIdx.x & 63;
    const int c = clsO[row];
    const int h = row >> 10;                 // 1024 rows per hist group
    int base = (int)rlocal[row];
    #pragma unroll
    for (int cc = 0; cc < 3; ++cc)           // classes below c (wave-uniform)
        if (cc < c) {
            #pragma unroll
            for (int hh = 0; hh < NH; ++hh) base += cntP[hh * 4 + cc];
        }
    #pragma unroll
    for (int hh = 0; hh < NH - 1; ++hh)      // earlier hist groups, same class
        if (hh < h) base += cntP[hh * 4 + c];

    const float2 v = *(const float2*)(F + row * ND + lane * 2);
    float ss = v.x * v.x + v.y * v.y;
    #pragma unroll
    for (int m = 1; m < 64; m <<= 1) ss += __shfl_xor(ss, m, 64);
    const float inv = rsqrtf(fmaxf(ss, 1e-24f));
    ushort2 st; st.x = f2bf(v.x * inv); st.y = f2bf(v.y * inv);
    *(ushort2*)(G + base * ND + lane * 2) = st;
    if (lane == 0) clsS[base] = (unsigned char)c;
}

// Stage one 64-row panel: wave wu stages rows wu*16..wu*16+15.
// Lane l -> row pr = wu*16 + 4*j + (l>>4), slot l&15 holds global chunk
// (slot - pr) & 15  (rotation; read side applies the same permutation).
__device__ __forceinline__ void stage_panel(
    const unsigned short* __restrict__ G, unsigned short* Blds,
    int rbase, int wu, int lrow4, int lpos)
{
    #pragma unroll
    for (int j = 0; j < 4; ++j) {
        const int pr = wu * 16 + j * 4 + lrow4;
        int rowG = rbase + pr;
        rowG = (rowG < NB - 1) ? rowG : (NB - 1);   // clamp (masked in compute)
        const int chunk = (lpos - pr) & 15;
        gload_lds16(G + rowG * ND + chunk * 8, Blds + (wu * 16 + j * 4) * ND);
    }
}

// MODE: 0 = stage-only (inactive wave), 1 = POS (Ep,Ls), 2 = NEG (En),
// 3 = weighted both (straddling waves only — rare after sorting).
// Double-buffered 2-phase: stage(p+1) issued BEFORE compute(p); the single
// end-of-panel __syncthreads (vmcnt drain) pays only the residual latency.
template<int MODE>
__device__ __forceinline__ void seg_panels(
    const unsigned short* __restrict__ G, unsigned short* Blds0,
    unsigned short* Blds1, const short8 (&A)[2][4],
    float (&Ep)[8], float (&En)[8], float (&Ls)[8],
    const float (&wp)[8], const float (&wn)[8],
    int cs, int ce, int p0, int p1, int wu, int lane)
{
    const int lrow4 = lane >> 4, lpos = lane & 15;
    const int q = lane >> 4, l16 = lane & 15;

    stage_panel(G, Blds0, cs + p0 * 64, wu, lrow4, lpos);
    __syncthreads();                       // panel p0 ready
    #pragma unroll 1
    for (int p = p0; p < p1; ++p) {
        const int cur = (p - p0) & 1;
        unsigned short* bufC = cur ? Blds1 : Blds0;
        if (p + 1 < p1)                    // prefetch next panel into other buf
            stage_panel(G, cur ? Blds0 : Blds1, cs + (p + 1) * 64, wu, lrow4, lpos);
        if (MODE != 0) {
            #pragma unroll
            for (int st = 0; st < 4; ++st) {
                const int j0 = cs + p * 64 + st * 16;
                if (j0 >= ce) break;       // wave-uniform tail cutoff
                short8 Bf[4];
                #pragma unroll
                for (int c = 0; c < 4; ++c) {
                    const int slot = (c * 4 + q + l16) & 15;    // rotation
                    Bf[c] = *(const short8*)&bufC[(st * 16 + l16) * ND + slot * 8];
                }
                f32x4 acc0 = {0.f, 0.f, 0.f, 0.f}, acc1 = {0.f, 0.f, 0.f, 0.f};
                #pragma unroll
                for (int c = 0; c < 4; ++c)
                    acc0 = __builtin_amdgcn_mfma_f32_16x16x32_bf16(A[0][c], Bf[c], acc0, 0, 0, 0);
                #pragma unroll
                for (int c = 0; c < 4; ++c)
                    acc1 = __builtin_amdgcn_mfma_f32_16x16x32_bf16(A[1][c], Bf[c], acc1, 0, 0, 0);
                if (j0 + 16 <= ce) {       // full subtile
                    #pragma unroll
                    for (int r = 0; r < 4; ++r) {
                        const float sv0 = acc0[r], sv1 = acc1[r];
                        const float e0 = fast_exp2(sv0 * EXPK);
                        const float e1 = fast_exp2(sv1 * EXPK);
                        if (MODE == 1) {
                            Ep[r] += e0;      Ls[r] += sv0;
                            Ep[4 + r] += e1;  Ls[4 + r] += sv1;
                        } else if (MODE == 2) {
                            En[r] += e0;      En[4 + r] += e1;
                        } else {
                            Ep[r]     = fmaf(wp[r],     e0,  Ep[r]);
                            Ls[r]     = fmaf(wp[r],     sv0, Ls[r]);
                            Ep[4 + r] = fmaf(wp[4 + r], e1,  Ep[4 + r]);
                            Ls[4 + r] = fmaf(wp[4 + r], sv1, Ls[4 + r]);
                            En[r]     = fmaf(wn[r],     e0, En[r]);
                            En[4 + r] = fmaf(wn[4 + r], e1, En[4 + r]);
                        }
                    }
                } else {                   // masked tail subtile
                    const float vm = ((j0 + l16) < ce) ? 1.f : 0.f;
                    #pragma unroll
                    for (int r = 0; r < 4; ++r) {
                        const float sv0 = acc0[r] * vm, sv1 = acc1[r] * vm;
                        const float e0 = fast_exp2(sv0 * EXPK) * vm;
                        const float e1 = fast_exp2(sv1 * EXPK) * vm;
                        if (MODE == 1) {
                            Ep[r] += e0;      Ls[r] += sv0;
                            Ep[4 + r] += e1;  Ls[4 + r] += sv1;
                        } else if (MODE == 2) {
                            En[r] += e0;      En[4 + r] += e1;
                        } else {
                            Ep[r]     = fmaf(wp[r],     e0,  Ep[r]);
                            Ls[r]     = fmaf(wp[r],     sv0, Ls[r]);
                            Ep[4 + r] = fmaf(wp[4 + r], e1,  Ep[4 + r]);
                            Ls[4 + r] = fmaf(wp[4 + r], sv1, Ls[4 + r]);
                            En[r]     = fmaf(wn[r],     e0, En[r]);
                            En[4 + r] = fmaf(wn[4 + r], e1, En[4 + r]);
                        }
                    }
                }
            }
        }
        __syncthreads();   // drains prefetch vmcnt + fences reads of bufC
    }
}

// Grid 64 i-blocks x 16 j-slices = 1024 blocks (4/CU).
__global__ __launch_bounds__(256) __attribute__((amdgpu_waves_per_eu(3, 4)))
void sim_kernel(
    const unsigned short* __restrict__ G, const unsigned char* __restrict__ clsS,
    const int* __restrict__ cntP,
    float* __restrict__ EpP, float* __restrict__ EnP, float* __restrict__ LsP)
{
    __shared__ unsigned short Blds[2][64 * 128];   // 2 x 16 KB

    const int ib = blockIdx.x & (NIB - 1);
    const int jb = blockIdx.x >> 6;          // 0..JS-1
    const int wave = threadIdx.x >> 6, lane = threadIdx.x & 63;
    const int q = lane >> 4, l16 = lane & 15;
    const int ri = ib * 128 + wave * 32;
    const int wu = __builtin_amdgcn_readfirstlane(wave);

    short8 A[2][4];
    #pragma unroll
    for (int t = 0; t < 2; ++t)
        #pragma unroll
        for (int c = 0; c < 4; ++c)
            A[t][c] = *(const short8*)(G + (ri + 16 * t + l16) * ND + c * 32 + q * 8);

    // this lane's 8 output-row classes (C/D row = 16t + 4q + r)
    const unsigned int rcLo = *(const unsigned int*)(clsS + ri + 4 * q);
    const unsigned int rcHi = *(const unsigned int*)(clsS + ri + 16 + 4 * q);
    const int wF = clsS[ri], wL = clsS[ri + 31];              // wave class range
    const int bF = clsS[ib * 128], bL = clsS[ib * 128 + 127]; // block class range

    float Ep[8], En[8], Ls[8];
    #pragma unroll
    for (int i = 0; i < 8; ++i) { Ep[i] = 0.f; En[i] = 0.f; Ls[i] = 0.f; }
    float wp[8], wn[8];   // written only on the (rare) straddle path

    int cs = 0;
    #pragma unroll 1
    for (int s = 0; s < 4; ++s) {
        int len = 0;
        #pragma unroll
        for (int h = 0; h < NH; ++h) len += cntP[h * 4 + s];
        const int ce = cs + len;
        const int s1 = s ^ 1, s2 = s ^ 2;
        const bool aPb = (s1 >= bF) && (s1 <= bL);   // block-uniform activity
        const bool aNb = (s2 >= bF) && (s2 <= bL);
        if (aPb || aNb) {
            const int np = (len + 63) >> 6;          // 64-row panels
            const int p0 = (jb * np) >> 4;           // this block's panel range
            const int p1 = ((jb + 1) * np) >> 4;
            if (p0 < p1) {
                if (wF == wL) {                       // pure-class wave (common)
                    if (s1 == wF)
                        seg_panels<1>(G, Blds[0], Blds[1], A, Ep, En, Ls, wp, wn, cs, ce, p0, p1, wu, lane);
                    else if (s2 == wF)
                        seg_panels<2>(G, Blds[0], Blds[1], A, Ep, En, Ls, wp, wn, cs, ce, p0, p1, wu, lane);
                    else
                        seg_panels<0>(G, Blds[0], Blds[1], A, Ep, En, Ls, wp, wn, cs, ce, p0, p1, wu, lane);
                } else {                              // straddling wave (rare)
                    #pragma unroll
                    for (int r = 0; r < 4; ++r) {
                        const int cLo = (rcLo >> (8 * r)) & 0xff;
                        const int cHi = (rcHi >> (8 * r)) & 0xff;
                        wp[r]     = (cLo == s1) ? 1.f : 0.f;
                        wp[4 + r] = (cHi == s1) ? 1.f : 0.f;
                        wn[r]     = (cLo == s2) ? 1.f : 0.f;
                        wn[4 + r] = (cHi == s2) ? 1.f : 0.f;
                    }
                    seg_panels<3>(G, Blds[0], Blds[1], A, Ep, En, Ls, wp, wn, cs, ce, p0, p1, wu, lane);
                }
            }
        }
        cs = ce;
    }

    // reduce across the 16 column-lanes
    #pragma unroll
    for (int m = 1; m < 16; m <<= 1)
        #pragma unroll
        for (int i = 0; i < 8; ++i) {
            Ep[i] += __shfl_xor(Ep[i], m, 64);
            En[i] += __shfl_xor(En[i], m, 64);
            Ls[i] += __shfl_xor(Ls[i], m, 64);
        }
    if (l16 == 0) {
        #pragma unroll
        for (int t = 0; t < 2; ++t)
            #pragma unroll
            for (int r = 0; r < 4; ++r) {
                const int row = ri + 16 * t + 4 * q + r;
                const int i = t * 4 + r;
                EpP[jb * NB + row] = Ep[i];   // plain stores, unique writer
                EnP[jb * NB + row] = En[i];
                LsP[jb * NB + row] = Ls[i];
            }
    }
}

__global__ __launch_bounds__(256) void finalize_kernel(
    const float* __restrict__ EpP, const float* __restrict__ EnP,
    const float* __restrict__ LsP, const unsigned char* __restrict__ clsS,
    const int* __restrict__ cntP, float* __restrict__ out)
{
    const int i = blockIdx.x * 256 + threadIdx.x;
    int tot[4] = {0, 0, 0, 0};
    #pragma unroll
    for (int hh = 0; hh < NH; ++hh)
        #pragma unroll
        for (int cc = 0; cc < 4; ++cc) tot[cc] += cntP[hh * 4 + cc];
    const int c = clsS[i];
    const int pc = c ^ 1, nc = c ^ 2;
    const int pcnt = (pc == 0) ? tot[0] : (pc == 1) ? tot[1] : (pc == 2) ? tot[2] : tot[3];
    const int ncnt = (nc == 0) ? tot[0] : (nc == 1) ? tot[1] : (nc == 2) ? tot[2] : tot[3];
    float ep = 0.f, en = 0.f, ls = 0.f;
    #pragma unroll
    for (int jb = 0; jb < JS; ++jb) {
        ep += EpP[jb * NB + i];
        en += EnP[jb * NB + i];
        ls += LsP[jb * NB + i];
    }
    float contrib = 0.0f;
    if (pcnt > 0 && ncnt > 0) {
        const float ld = logf(ep + en);
        contrib = -(TEMP_INV * ls - (float)pcnt * ld) / ((float)pcnt * (float)NB);
    }
    #pragma unroll
    for (int m = 1; m < 64; m <<= 1) contrib += __shfl_xor(contrib, m, 64);
    __shared__ float wsum[4];
    if ((threadIdx.x & 63) == 0) wsum[threadIdx.x >> 6] = contrib;
    __syncthreads();
    if (threadIdx.x == 0)
        atomicAdd(out, wsum[0] + wsum[1] + wsum[2] + wsum[3]);
}

extern "C" void kernel_launch(void* const* d_in, const int* in_sizes, int n_in,
                              void* d_out, int out_size, void* d_ws, size_t ws_size,
                              hipStream_t stream) {
    const float* F = (const float*)d_in[0];
    const int* dix = (const int*)d_in[1];
    const int* tt  = (const int*)d_in[2];
    const int* tp  = (const int*)d_in[3];
    float* out = (float*)d_out;

    char* ws = (char*)d_ws;
    unsigned short* G   = (unsigned short*)(ws + OFF_G);
    unsigned char* clsS = (unsigned char*)(ws + OFF_CLS);
    int* cntP           = (int*)(ws + OFF_CNT);
    float* EpP          = (float*)(ws + OFF_EPP);
    float* EnP          = (float*)(ws + OFF_ENP);
    float* LsP          = (float*)(ws + OFF_LSP);
    unsigned char* clsO = (unsigned char*)(ws + OFF_CO);   // aliases EpP (dead
    unsigned short* rl  = (unsigned short*)(ws + OFF_RL);  //  before sim writes)

    classify_kernel<<<NH, 1024, 0, stream>>>(dix, tt, tp, clsO, rl, cntP, out);
    normscatter_kernel<<<2048, 256, 0, stream>>>(F, clsO, rl, cntP, G, clsS);
    sim_kernel<<<NIB * JS, 256, 0, stream>>>(G, clsS, cntP, EpP, EnP, LsP);
    finalize_kernel<<<NB / 256, 256, 0, stream>>>(EpP, EnP, LsP, clsS, cntP, out);
}